// Round 1
// baseline (112.543 us; speedup 1.0000x reference)
//
#include <hip/hip_runtime.h>

// Problem constants
#define NB 4      // B
#define CA 128    // audio channels
#define CV 512    // video channels
#define NHH 8     // heads
#define TA 64     // audio time
#define FF 64     // audio freq
#define TV 256    // video time
#define REPC 4    // Cv/Ca
#define EPSV 1e-5f

__device__ __forceinline__ float waveReduceSum(float x) {
  #pragma unroll
  for (int off = 32; off; off >>= 1) x += __shfl_xor(x, off);
  return x;
}
__device__ __forceinline__ float waveReduceMax(float x) {
  #pragma unroll
  for (int off = 32; off; off >>= 1) x = fmaxf(x, __shfl_xor(x, off));
  return x;
}

// acc layout per b (8 floats):
// 0: sum of (a_exp*p1_w+p1_b)          1: sum of squares of same
// 2: sum of (a_exp*p2_w+p2_b)          3: sum of squares
// 4: sum of (v_rep*f1_w+f1_b)          5: sum of squares
// 6: sum of (video*f2_w+f2_b)          7: sum of squares
__global__ __launch_bounds__(256) void stats_kernel(
    const float* __restrict__ audio, const float* __restrict__ video,
    const float* __restrict__ p1_w, const float* __restrict__ p1_b,
    const float* __restrict__ p2_w, const float* __restrict__ p2_b,
    const float* __restrict__ f1_w, const float* __restrict__ f1_b,
    const float* __restrict__ f2_w, const float* __restrict__ f2_b,
    float* __restrict__ acc)
{
  const int bid = blockIdx.x;
  const int tid = threadIdx.x;
  const int wv = tid >> 6, ln = tid & 63;
  __shared__ float reds[8];

  if (bid < NB * CA) {
    // ---- audio slab (b, ca): raw S = sum a, Q = sum a^2 over Ta*F ----
    const int b = bid >> 7, ca = bid & (CA - 1);
    const float* ap = audio + (size_t)(b * CA + ca) * (TA * FF);
    float s = 0.f, q = 0.f;
    #pragma unroll
    for (int i = 0; i < (TA * FF) / 256; ++i) {
      float a = ap[tid + i * 256];
      s += a; q += a * a;
    }
    s = waveReduceSum(s); q = waveReduceSum(q);
    if (ln == 0) { reds[wv] = s; reds[4 + wv] = q; }
    __syncthreads();
    if (tid == 0) {
      float S = reds[0] + reds[1] + reds[2] + reds[3];
      float Q = reds[4] + reds[5] + reds[6] + reds[7];
      // fold the 4 replicated channels' params
      float W1 = 0, W1q = 0, W1pb = 0, C1 = 0, C1q = 0;
      float W2 = 0, W2q = 0, W2pb = 0, C2 = 0, C2q = 0;
      #pragma unroll
      for (int r = 0; r < REPC; ++r) {
        int c = ca * REPC + r;
        float w = p1_w[c], bb = p1_b[c];
        W1 += w; W1q += w * w; W1pb += w * bb; C1 += bb; C1q += bb * bb;
        float w2 = p2_w[c], b2 = p2_b[c];
        W2 += w2; W2q += w2 * w2; W2pb += w2 * b2; C2 += b2; C2q += b2 * b2;
      }
      const float NE = (float)(TA * FF);
      atomicAdd(&acc[b * 8 + 0], W1 * S + NE * C1);
      atomicAdd(&acc[b * 8 + 1], W1q * Q + 2.f * W1pb * S + NE * C1q);
      atomicAdd(&acc[b * 8 + 2], W2 * S + NE * C2);
      atomicAdd(&acc[b * 8 + 3], W2q * Q + 2.f * W2pb * S + NE * C2q);
    }
  } else {
    // ---- video rows: each wave handles one (b,c), lanes stride over Tv ----
    const int vb = bid - NB * CA;
    const int b = vb >> 7;
    const int c = ((vb & 127) << 2) + wv;
    const float* vp = video + (size_t)(b * CV + c) * TV;
    float s = 0.f, q = 0.f;
    #pragma unroll
    for (int i = 0; i < TV / 64; ++i) {
      float v = vp[ln + i * 64];
      s += v; q += v * v;
    }
    s = waveReduceSum(s); q = waveReduceSum(q);
    if (ln == 0) {
      float Wf = 0, Wfq = 0, Wfb = 0, Cf = 0, Cfq = 0;
      #pragma unroll
      for (int h = 0; h < NHH; ++h) {
        int j = c * NHH + h;
        float fw = f1_w[j], fb = f1_b[j];
        Wf += fw; Wfq += fw * fw; Wfb += fw * fb; Cf += fb; Cfq += fb * fb;
      }
      const float NT = (float)TV;
      atomicAdd(&acc[b * 8 + 4], Wf * s + NT * Cf);
      atomicAdd(&acc[b * 8 + 5], Wfq * q + 2.f * Wfb * s + NT * Cfq);
      float w2 = f2_w[c], b2 = f2_b[c];
      atomicAdd(&acc[b * 8 + 6], w2 * s + NT * b2);
      atomicAdd(&acc[b * 8 + 7], w2 * w2 * q + 2.f * w2 * b2 * s + NT * b2 * b2);
    }
  }
}

// One block per (b, c). 256 threads = 4 waves.
__global__ __launch_bounds__(256) void out_kernel(
    const float* __restrict__ audio, const float* __restrict__ video,
    const float* __restrict__ p1_w, const float* __restrict__ p1_b,
    const float* __restrict__ p1_g, const float* __restrict__ p1_be,
    const float* __restrict__ p2_w, const float* __restrict__ p2_b,
    const float* __restrict__ p2_g, const float* __restrict__ p2_be,
    const float* __restrict__ f1_w, const float* __restrict__ f1_g,
    const float* __restrict__ f2_w, const float* __restrict__ f2_b,
    const float* __restrict__ f2_g, const float* __restrict__ f2_be,
    const float* __restrict__ acc, float* __restrict__ out)
{
  const int bid = blockIdx.x;
  const int b = bid >> 9;          // / CV
  const int c = bid & (CV - 1);
  const int ca = c >> 2;
  const int tid = threadIdx.x;
  const int wv = tid >> 6, ln = tid & 63;

  // finalize per-batch norm scalars (redundant per block; 8 cached loads)
  const float invNa = 1.f / (float)(CV * TA * FF);
  const float invN3 = 1.f / (float)(CV * NHH * TV);
  const float invN4 = 1.f / (float)(CV * TV);
  float mu1 = acc[b * 8 + 0] * invNa;
  float rs1 = rsqrtf(fmaxf(acc[b * 8 + 1] * invNa - mu1 * mu1, 0.f) + EPSV);
  float mu2 = acc[b * 8 + 2] * invNa;
  float rs2 = rsqrtf(fmaxf(acc[b * 8 + 3] * invNa - mu2 * mu2, 0.f) + EPSV);
  float mu3 = acc[b * 8 + 4] * invN3;
  float rs3 = rsqrtf(fmaxf(acc[b * 8 + 5] * invN3 - mu3 * mu3, 0.f) + EPSV);
  float mu4 = acc[b * 8 + 6] * invN4;
  float rs4 = rsqrtf(fmaxf(acc[b * 8 + 7] * invN4 - mu4 * mu4, 0.f) + EPSV);

  // per-(b,c) affine constants
  const float A1 = p1_w[c] * rs1 * p1_g[c];
  const float B1 = (p1_b[c] - mu1) * rs1 * p1_g[c] + p1_be[c];
  const float A2 = p2_w[c] * rs2 * p2_g[c];
  const float B2 = (p2_b[c] - mu2) * rs2 * p2_g[c] + p2_be[c];
  float sw = 0.f;
  #pragma unroll
  for (int h = 0; h < NHH; ++h) sw += f1_w[c * NHH + h] * f1_g[c * NHH + h];
  const float alpha = rs3 * sw * (1.f / NHH);   // softmax logit slope (consts cancel)
  const float A4 = f2_w[c] * rs4 * f2_g[c];
  const float B4 = (f2_b[c] - mu4) * rs4 * f2_g[c] + f2_be[c];

  __shared__ float sval[TA], sgate[TA], reds[8];

  // audio slab reduction: wave wv handles rows [wv*16, wv*16+16), lane = f
  const float* ap = audio + (size_t)(b * CA + ca) * (TA * FF);
  #pragma unroll
  for (int k = 0; k < TA / 4; ++k) {
    int ta = wv * (TA / 4) + k;
    float a = ap[ta * FF + ln];
    float sa = waveReduceSum(a);
    float sg = waveReduceSum(fmaxf(a * A2 + B2, 0.f));
    if (ln == 0) {
      sval[ta] = A1 * sa + (float)FF * B1;   // sum_f a_val
      sgate[ta] = sg;                        // sum_f relu(a_gate)
    }
  }

  // video: softmax over t (256 threads) + fused output
  const float v = video[(size_t)(b * CV + c) * TV + tid];
  float logit = alpha * v;
  float m = waveReduceMax(logit);
  if (ln == 0) reds[wv] = m;
  __syncthreads();   // also covers sval/sgate visibility
  m = fmaxf(fmaxf(reds[0], reds[1]), fmaxf(reds[2], reds[3]));
  float e = __expf(logit - m);
  float z = waveReduceSum(e);
  if (ln == 0) reds[4 + wv] = z;
  __syncthreads();
  z = reds[4] + reds[5] + reds[6] + reds[7];
  float attn = e / z;
  float vkey = v * A4 + B4;
  out[(size_t)(b * CV + c) * TV + tid] = attn * sval[tid >> 2] + vkey * sgate[tid >> 2] + v;
}

extern "C" void kernel_launch(void* const* d_in, const int* in_sizes, int n_in,
                              void* d_out, int out_size, void* d_ws, size_t ws_size,
                              hipStream_t stream) {
  const float* audio = (const float*)d_in[0];
  const float* video = (const float*)d_in[1];
  const float* p1_w  = (const float*)d_in[2];
  const float* p1_b  = (const float*)d_in[3];
  const float* p1_g  = (const float*)d_in[4];
  const float* p1_be = (const float*)d_in[5];
  const float* p2_w  = (const float*)d_in[6];
  const float* p2_b  = (const float*)d_in[7];
  const float* p2_g  = (const float*)d_in[8];
  const float* p2_be = (const float*)d_in[9];
  const float* f1_w  = (const float*)d_in[10];
  const float* f1_b  = (const float*)d_in[11];
  const float* f1_g  = (const float*)d_in[12];
  const float* f1_be = (const float*)d_in[13];  // cancels in softmax, unused
  const float* f2_w  = (const float*)d_in[14];
  const float* f2_b  = (const float*)d_in[15];
  const float* f2_g  = (const float*)d_in[16];
  const float* f2_be = (const float*)d_in[17];
  (void)f1_be; (void)in_sizes; (void)n_in; (void)out_size; (void)ws_size;

  float* acc = (float*)d_ws;           // 32 floats used
  float* out = (float*)d_out;

  hipMemsetAsync(acc, 0, 64 * sizeof(float), stream);

  stats_kernel<<<NB * CA + NB * CV / 4, 256, 0, stream>>>(
      audio, video, p1_w, p1_b, p2_w, p2_b, f1_w, f1_b, f2_w, f2_b, acc);

  out_kernel<<<NB * CV, 256, 0, stream>>>(
      audio, video,
      p1_w, p1_b, p1_g, p1_be,
      p2_w, p2_b, p2_g, p2_be,
      f1_w, f1_g, f2_w, f2_b, f2_g, f2_be,
      acc, out);
}

// Round 2
// 19.732 us; speedup vs baseline: 5.7036x; 5.7036x over previous
//
#include <hip/hip_runtime.h>

// Problem constants
#define NB 4      // B
#define CA 128    // audio channels
#define CV 512    // video channels
#define NHH 8     // heads
#define TA 64     // audio time
#define FF 64     // audio freq
#define TV 256    // video time
#define REPC 4    // Cv/Ca
#define EPSV 1e-5f

// ws layout (floats):
// [0 .. 4095]    partials: accumulator (q8,b) at ws[q8*512 + b*128 + idx], idx=0..127
//                q8 = 0..3 audio (p1 sum, p1 sumsq, p2 sum, p2 sumsq)
//                q8 = 4..7 video (f1 sum, f1 sumsq, f2 sum, f2 sumsq)
// [4096 .. 4127] finals: acc[b*8 + q8]

__device__ __forceinline__ float waveReduceSum(float x) {
  #pragma unroll
  for (int off = 32; off; off >>= 1) x += __shfl_xor(x, off);
  return x;
}
__device__ __forceinline__ float waveReduceMax(float x) {
  #pragma unroll
  for (int off = 32; off; off >>= 1) x = fmaxf(x, __shfl_xor(x, off));
  return x;
}
__device__ __forceinline__ float group16ReduceSum(float x) {
  #pragma unroll
  for (int off = 8; off; off >>= 1) x += __shfl_xor(x, off);
  return x;
}

__global__ __launch_bounds__(256) void stats_kernel(
    const float* __restrict__ audio, const float* __restrict__ video,
    const float* __restrict__ p1_w, const float* __restrict__ p1_b,
    const float* __restrict__ p2_w, const float* __restrict__ p2_b,
    const float* __restrict__ f1_w, const float* __restrict__ f1_b,
    const float* __restrict__ f2_w, const float* __restrict__ f2_b,
    float* __restrict__ ws)
{
  const int bid = blockIdx.x;
  const int tid = threadIdx.x;
  const int wv = tid >> 6, ln = tid & 63;
  __shared__ float red1[4], red2[4], fold[4][4];

  if (bid < NB * CA) {
    // ---- audio slab (b, ca): S = sum a, Q = sum a^2 over Ta*F (4096 elems) ----
    const int b = bid >> 7, ca = bid & (CA - 1);
    const float4* ap4 = (const float4*)(audio + (size_t)(b * CA + ca) * (TA * FF));
    float s = 0.f, q = 0.f;
    #pragma unroll
    for (int i = 0; i < 4; ++i) {
      float4 v = ap4[tid + i * 256];
      s += v.x + v.y + v.z + v.w;
      q += v.x * v.x + v.y * v.y + v.z * v.z + v.w * v.w;
    }
    s = waveReduceSum(s); q = waveReduceSum(q);
    if (ln == 0) { red1[wv] = s; red2[wv] = q; }
    __syncthreads();
    if (tid == 0) {
      float S = red1[0] + red1[1] + red1[2] + red1[3];
      float Q = red2[0] + red2[1] + red2[2] + red2[3];
      float W1 = 0, W1q = 0, W1pb = 0, C1 = 0, C1q = 0;
      float W2 = 0, W2q = 0, W2pb = 0, C2 = 0, C2q = 0;
      #pragma unroll
      for (int r = 0; r < REPC; ++r) {
        int c = ca * REPC + r;
        float w = p1_w[c], bb = p1_b[c];
        W1 += w; W1q += w * w; W1pb += w * bb; C1 += bb; C1q += bb * bb;
        float w2 = p2_w[c], b2 = p2_b[c];
        W2 += w2; W2q += w2 * w2; W2pb += w2 * b2; C2 += b2; C2q += b2 * b2;
      }
      const float NE = (float)(TA * FF);
      const int base = b * 128 + ca;
      ws[0 * 512 + base] = W1 * S + NE * C1;
      ws[1 * 512 + base] = W1q * Q + 2.f * W1pb * S + NE * C1q;
      ws[2 * 512 + base] = W2 * S + NE * C2;
      ws[3 * 512 + base] = W2q * Q + 2.f * W2pb * S + NE * C2q;
    }
  } else {
    // ---- video: 4 channels per block (wave wv -> channel), float4/lane ----
    const int vb = bid - NB * CA;
    const int b = vb >> 7, vi = vb & 127;
    const int c = vi * 4 + wv;
    const float4* vp4 = (const float4*)(video + (size_t)(b * CV + c) * TV);
    float4 v = vp4[ln];
    float s = v.x + v.y + v.z + v.w;
    float q = v.x * v.x + v.y * v.y + v.z * v.z + v.w * v.w;
    s = waveReduceSum(s); q = waveReduceSum(q);
    if (ln == 0) {
      float Wf = 0, Wfq = 0, Wfb = 0, Cf = 0, Cfq = 0;
      #pragma unroll
      for (int h = 0; h < NHH; ++h) {
        int j = c * NHH + h;
        float fw = f1_w[j], fb = f1_b[j];
        Wf += fw; Wfq += fw * fw; Wfb += fw * fb; Cf += fb; Cfq += fb * fb;
      }
      const float NT = (float)TV;
      float w2 = f2_w[c], b2 = f2_b[c];
      fold[wv][0] = Wf * s + NT * Cf;
      fold[wv][1] = Wfq * q + 2.f * Wfb * s + NT * Cfq;
      fold[wv][2] = w2 * s + NT * b2;
      fold[wv][3] = w2 * w2 * q + 2.f * w2 * b2 * s + NT * b2 * b2;
    }
    __syncthreads();
    if (tid < 4) {
      float p = fold[0][tid] + fold[1][tid] + fold[2][tid] + fold[3][tid];
      ws[(4 + tid) * 512 + b * 128 + vi] = p;
    }
  }
}

// 1 block, 256 threads: reduce 128 partials for each of 32 accumulators.
__global__ __launch_bounds__(256) void finalize_kernel(float* __restrict__ ws)
{
  const int tid = threadIdx.x;
  const int wv = tid >> 6, ln = tid & 63;
  #pragma unroll
  for (int r = 0; r < 8; ++r) {
    int a = wv * 8 + r;                 // (q8 = a>>2, b = a&3)
    const float* p = ws + (a >> 2) * 512 + (a & 3) * 128;
    float s = p[ln] + p[64 + ln];
    s = waveReduceSum(s);
    if (ln == 0) ws[4096 + (a & 3) * 8 + (a >> 2)] = s;
  }
}

// One block per (b, ca): 4 channels share one audio slab. 256 threads = 4 waves.
__global__ __launch_bounds__(256) void out_kernel(
    const float* __restrict__ audio, const float* __restrict__ video,
    const float* __restrict__ p1_w, const float* __restrict__ p1_b,
    const float* __restrict__ p1_g, const float* __restrict__ p1_be,
    const float* __restrict__ p2_w, const float* __restrict__ p2_b,
    const float* __restrict__ p2_g, const float* __restrict__ p2_be,
    const float* __restrict__ f1_w, const float* __restrict__ f1_g,
    const float* __restrict__ f2_w, const float* __restrict__ f2_b,
    const float* __restrict__ f2_g, const float* __restrict__ f2_be,
    const float* __restrict__ ws, float* __restrict__ out)
{
  const int bid = blockIdx.x;
  const int b = bid >> 7;              // / CA
  const int ca = bid & (CA - 1);
  const int c0 = ca * 4;
  const int tid = threadIdx.x;
  const int wv = tid >> 6, ln = tid & 63;

  // per-batch norm scalars
  const float* acc = ws + 4096;
  const float invNa = 1.f / (float)(CV * TA * FF);
  const float invN3 = 1.f / (float)(CV * NHH * TV);
  const float invN4 = 1.f / (float)(CV * TV);
  float mu1 = acc[b * 8 + 0] * invNa;
  float rs1 = rsqrtf(fmaxf(acc[b * 8 + 1] * invNa - mu1 * mu1, 0.f) + EPSV);
  float mu2 = acc[b * 8 + 2] * invNa;
  float rs2 = rsqrtf(fmaxf(acc[b * 8 + 3] * invNa - mu2 * mu2, 0.f) + EPSV);
  float mu3 = acc[b * 8 + 4] * invN3;
  float rs3 = rsqrtf(fmaxf(acc[b * 8 + 5] * invN3 - mu3 * mu3, 0.f) + EPSV);
  float mu4 = acc[b * 8 + 6] * invN4;
  float rs4 = rsqrtf(fmaxf(acc[b * 8 + 7] * invN4 - mu4 * mu4, 0.f) + EPSV);

  // gate affine consts for all 4 channels of this slab (static-indexed regs)
  float A2a[4], B2a[4];
  #pragma unroll
  for (int cc = 0; cc < 4; ++cc) {
    int c = c0 + cc;
    A2a[cc] = p2_w[c] * rs2 * p2_g[c];
    B2a[cc] = (p2_b[c] - mu2) * rs2 * p2_g[c] + p2_be[c];
  }

  __shared__ float ssa[TA];        // raw row sums  sum_f audio[b,ca,ta,:]
  __shared__ float sg[4][TA];      // per-channel   sum_f relu(gate)

  // ---- audio phase: wave wv handles rows [wv*16, wv*16+16), 4 rows/iter ----
  const float4* ap4 = (const float4*)(audio + (size_t)(b * CA + ca) * (TA * FF));
  #pragma unroll
  for (int i = 0; i < 4; ++i) {
    int rbase = wv * 16 + i * 4;
    float4 v = ap4[rbase * 16 + ln];           // lane ln: row rbase+(ln>>4), cols (ln&15)*4..+3
    float sa = v.x + v.y + v.z + v.w;
    float g0, g1, g2, g3;
    {
      g0 = fmaxf(v.x * A2a[0] + B2a[0], 0.f) + fmaxf(v.y * A2a[0] + B2a[0], 0.f)
         + fmaxf(v.z * A2a[0] + B2a[0], 0.f) + fmaxf(v.w * A2a[0] + B2a[0], 0.f);
      g1 = fmaxf(v.x * A2a[1] + B2a[1], 0.f) + fmaxf(v.y * A2a[1] + B2a[1], 0.f)
         + fmaxf(v.z * A2a[1] + B2a[1], 0.f) + fmaxf(v.w * A2a[1] + B2a[1], 0.f);
      g2 = fmaxf(v.x * A2a[2] + B2a[2], 0.f) + fmaxf(v.y * A2a[2] + B2a[2], 0.f)
         + fmaxf(v.z * A2a[2] + B2a[2], 0.f) + fmaxf(v.w * A2a[2] + B2a[2], 0.f);
      g3 = fmaxf(v.x * A2a[3] + B2a[3], 0.f) + fmaxf(v.y * A2a[3] + B2a[3], 0.f)
         + fmaxf(v.z * A2a[3] + B2a[3], 0.f) + fmaxf(v.w * A2a[3] + B2a[3], 0.f);
    }
    sa = group16ReduceSum(sa);
    g0 = group16ReduceSum(g0);
    g1 = group16ReduceSum(g1);
    g2 = group16ReduceSum(g2);
    g3 = group16ReduceSum(g3);
    if ((ln & 15) == 0) {
      int rr = rbase + (ln >> 4);
      ssa[rr] = sa;
      sg[0][rr] = g0; sg[1][rr] = g1; sg[2][rr] = g2; sg[3][rr] = g3;
    }
  }

  // ---- per-wave channel consts ----
  const int c = c0 + wv;
  const float A1 = p1_w[c] * rs1 * p1_g[c];
  const float B1 = (p1_b[c] - mu1) * rs1 * p1_g[c] + p1_be[c];
  float sw = 0.f;
  #pragma unroll
  for (int h = 0; h < NHH; ++h) sw += f1_w[c * NHH + h] * f1_g[c * NHH + h];
  const float alpha = rs3 * sw * (1.f / NHH);
  const float A4 = f2_w[c] * rs4 * f2_g[c];
  const float B4 = (f2_b[c] - mu4) * rs4 * f2_g[c] + f2_be[c];

  __syncthreads();

  // ---- video phase: wave wv owns channel c; lane ln covers t = ln*4..ln*4+3 ----
  const float4* vp4 = (const float4*)(video + (size_t)(b * CV + c) * TV);
  float4 v = vp4[ln];
  float l0 = alpha * v.x, l1 = alpha * v.y, l2 = alpha * v.z, l3 = alpha * v.w;
  float m = fmaxf(fmaxf(l0, l1), fmaxf(l2, l3));
  m = waveReduceMax(m);
  float e0 = __expf(l0 - m), e1 = __expf(l1 - m), e2 = __expf(l2 - m), e3 = __expf(l3 - m);
  float z = waveReduceSum(e0 + e1 + e2 + e3);
  float iz = 1.f / z;
  float sval = A1 * ssa[ln] + (float)FF * B1;   // a_val row-sum for t>>2 == ln
  float sgate = sg[wv][ln];
  float4 o;
  o.x = e0 * iz * sval + (v.x * A4 + B4) * sgate + v.x;
  o.y = e1 * iz * sval + (v.y * A4 + B4) * sgate + v.y;
  o.z = e2 * iz * sval + (v.z * A4 + B4) * sgate + v.z;
  o.w = e3 * iz * sval + (v.w * A4 + B4) * sgate + v.w;
  ((float4*)(out + (size_t)(b * CV + c) * TV))[ln] = o;
}

extern "C" void kernel_launch(void* const* d_in, const int* in_sizes, int n_in,
                              void* d_out, int out_size, void* d_ws, size_t ws_size,
                              hipStream_t stream) {
  const float* audio = (const float*)d_in[0];
  const float* video = (const float*)d_in[1];
  const float* p1_w  = (const float*)d_in[2];
  const float* p1_b  = (const float*)d_in[3];
  const float* p1_g  = (const float*)d_in[4];
  const float* p1_be = (const float*)d_in[5];
  const float* p2_w  = (const float*)d_in[6];
  const float* p2_b  = (const float*)d_in[7];
  const float* p2_g  = (const float*)d_in[8];
  const float* p2_be = (const float*)d_in[9];
  const float* f1_w  = (const float*)d_in[10];
  const float* f1_b  = (const float*)d_in[11];
  const float* f1_g  = (const float*)d_in[12];
  const float* f2_w  = (const float*)d_in[14];
  const float* f2_b  = (const float*)d_in[15];
  const float* f2_g  = (const float*)d_in[16];
  const float* f2_be = (const float*)d_in[17];
  (void)in_sizes; (void)n_in; (void)out_size; (void)ws_size;

  float* ws  = (float*)d_ws;
  float* out = (float*)d_out;

  stats_kernel<<<NB * CA + NB * CV / 4, 256, 0, stream>>>(
      audio, video, p1_w, p1_b, p2_w, p2_b, f1_w, f1_b, f2_w, f2_b, ws);

  finalize_kernel<<<1, 256, 0, stream>>>(ws);

  out_kernel<<<NB * CA, 256, 0, stream>>>(
      audio, video,
      p1_w, p1_b, p1_g, p1_be,
      p2_w, p2_b, p2_g, p2_be,
      f1_w, f1_g, f2_w, f2_b, f2_g, f2_be,
      ws, out);
}